// Round 1
// baseline (283.429 us; speedup 1.0000x reference)
//
#include <hip/hip_runtime.h>

typedef unsigned int u32;

#define N_PTS 480000
#define PPB   120000      // points per batch (B=4)
#define NKEY  131072      // 4 * 32^3 compact key space
#define NBLK_A 256
#define NBLK_B 512
#define NTILES 30000      // N_PTS / 16
#define SLOPE 0.01f

// order-preserving float <-> uint mapping for atomicMax (0 < map(any finite float))
__device__ __forceinline__ u32 mapf(float f) {
    u32 u = __float_as_uint(f);
    return (u & 0x80000000u) ? ~u : (u | 0x80000000u);
}
__device__ __forceinline__ float unmapf(u32 m) {
    u32 u = (m & 0x80000000u) ? (m ^ 0x80000000u) : ~m;
    return __uint_as_float(u);
}

// ---------------- kernel A: keys, occupancy flags, x-moment partials ----------------
__global__ __launch_bounds__(256) void kA(const float* __restrict__ pc,
                                          const int* __restrict__ pidx,
                                          u32* __restrict__ keys,
                                          u32* __restrict__ occ,
                                          float* __restrict__ pA) {
    int t = threadIdx.x;
    float a[14];
#pragma unroll
    for (int j = 0; j < 14; ++j) a[j] = 0.f;

    for (int n = blockIdx.x * 256 + t; n < N_PTS; n += gridDim.x * 256) {
        float4 x = ((const float4*)pc)[n];
        a[0] += x.x; a[1] += x.y; a[2] += x.z; a[3] += x.w;
        a[4] += x.x * x.x; a[5] += x.x * x.y; a[6]  += x.x * x.z; a[7]  += x.x * x.w;
        a[8] += x.y * x.y; a[9] += x.y * x.z; a[10] += x.y * x.w;
        a[11] += x.z * x.z; a[12] += x.z * x.w; a[13] += x.w * x.w;

        int i0 = pidx[3 * n], i1 = pidx[3 * n + 1], i2 = pidx[3 * n + 2];
        int bid = n / PPB;
        u32 key = (u32)(bid * 32768 + i0 * 1024 + i1 * 32 + i2);
        keys[n] = key;
        occ[key] = 1u;
    }

    __shared__ float red[256];
    for (int j = 0; j < 14; ++j) {
        red[t] = a[j];
        __syncthreads();
        for (int s = 128; s > 0; s >>= 1) {
            if (t < s) red[t] += red[t + s];
            __syncthreads();
        }
        if (t == 0) pA[blockIdx.x * 14 + j] = red[0];
        __syncthreads();
    }
}

// ---------------- kernel R1: reduce x-moments -> layer-1 BN scale/shift ----------------
__global__ __launch_bounds__(64) void kR1(const float* __restrict__ pA,
                                          const float* __restrict__ W1,
                                          const float* __restrict__ b1,
                                          const float* __restrict__ g1,
                                          const float* __restrict__ be1,
                                          float* __restrict__ stats1) {
    __shared__ double S[14];
    int t = threadIdx.x;
    if (t < 14) {
        double s = 0.0;
        for (int b = 0; b < NBLK_A; ++b) s += pA[b * 14 + t];
        S[t] = s;
    }
    __syncthreads();
    if (t < 16) {
        int c = t;
        double w[4];
#pragma unroll
        for (int i = 0; i < 4; ++i) w[i] = W1[i * 16 + c];
        double sx[4] = { S[0], S[1], S[2], S[3] };
        // Sxx upper triangle stored at S[4..13]: (0,0)(0,1)(0,2)(0,3)(1,1)(1,2)(1,3)(2,2)(2,3)(3,3)
        auto sxx = [&](int i, int j) -> double {
            if (i > j) { int k = i; i = j; j = k; }
            int base = (i == 0) ? 4 : (i == 1) ? 8 : (i == 2) ? 11 : 13;
            return S[base + (j - i)];
        };
        double su = 0.0;
        for (int i = 0; i < 4; ++i) su += sx[i] * w[i];
        double q = 0.0;
        for (int i = 0; i < 4; ++i)
            for (int j = 0; j < 4; ++j) q += w[i] * w[j] * sxx(i, j);
        double b = (double)b1[c];
        double sum   = su + b * (double)N_PTS;
        double sumsq = q + 2.0 * b * su + (double)N_PTS * b * b;
        double mean = sum / (double)N_PTS;
        double var  = sumsq / (double)N_PTS - mean * mean;
        float inv = rsqrtf((float)(var + 1e-5));
        float sc = g1[c] * inv;
        stats1[c]      = sc;
        stats1[16 + c] = be1[c] - (float)mean * sc;
    }
}

// ---------------- kernel B: per-channel sum/sumsq of layer-2 pre-activation ----------------
__global__ __launch_bounds__(256) void kB(const float* __restrict__ pc,
                                          const float* __restrict__ W1,
                                          const float* __restrict__ b1,
                                          const float* __restrict__ stats1,
                                          const float* __restrict__ W2,
                                          const float* __restrict__ b2,
                                          float* __restrict__ pB) {
    int t = threadIdx.x;
    __shared__ float shx[64];
    __shared__ float shh[16][16];

    int c1 = t & 15;
    float w1c[4];
#pragma unroll
    for (int i = 0; i < 4; ++i) w1c[i] = W1[i * 16 + c1];
    float b1c = b1[c1], sc1 = stats1[c1], sf1 = stats1[16 + c1];

    int c2 = t & 63;
    float w2c[16];
#pragma unroll
    for (int k = 0; k < 16; ++k) w2c[k] = W2[k * 64 + c2];
    float b2c = b2[c2];
    int psub = t >> 6;

    float accf = 0.f, accf2 = 0.f;
    for (int tile = blockIdx.x; tile < NTILES; tile += gridDim.x) {
        int base = tile * 16;
        if (t < 64) shx[t] = pc[base * 4 + t];
        __syncthreads();
        {
            int p = t >> 4;
            float hp = b1c + shx[p * 4 + 0] * w1c[0] + shx[p * 4 + 1] * w1c[1]
                           + shx[p * 4 + 2] * w1c[2] + shx[p * 4 + 3] * w1c[3];
            float z = hp * sc1 + sf1;
            shh[p][c1] = (z >= 0.f) ? z : SLOPE * z;
        }
        __syncthreads();
#pragma unroll
        for (int i = 0; i < 4; ++i) {
            int p = (psub << 2) + i;
            float f = b2c;
#pragma unroll
            for (int k = 0; k < 16; ++k) f += shh[p][k] * w2c[k];
            accf += f;
            accf2 += f * f;
        }
        __syncthreads();
    }

    __shared__ float r1[256], r2[256];
    r1[t] = accf; r2[t] = accf2;
    __syncthreads();
    if (t < 64) {
        float s1 = r1[t] + r1[t + 64] + r1[t + 128] + r1[t + 192];
        float s2 = r2[t] + r2[t + 64] + r2[t + 128] + r2[t + 192];
        pB[blockIdx.x * 128 + t]      = s1;
        pB[blockIdx.x * 128 + 64 + t] = s2;
    }
}

// ---------------- kernel R2: reduce layer-2 stats -> BN scale/shift ----------------
__global__ __launch_bounds__(64) void kR2(const float* __restrict__ pB,
                                          const float* __restrict__ g2,
                                          const float* __restrict__ be2,
                                          float* __restrict__ stats2) {
    int c = threadIdx.x;  // 64 threads, one per channel
    double sf = 0.0, sf2 = 0.0;
    for (int b = 0; b < NBLK_B; ++b) {
        sf  += pB[b * 128 + c];
        sf2 += pB[b * 128 + 64 + c];
    }
    double mean = sf / (double)N_PTS;
    double var  = sf2 / (double)N_PTS - mean * mean;
    float inv = rsqrtf((float)(var + 1e-5));
    float sc = g2[c] * inv;
    stats2[c]      = sc;
    stats2[64 + c] = be2[c] - (float)mean * sc;
}

// ---------------- scan: occupancy -> exclusive rank + n_uni ----------------
__global__ __launch_bounds__(1024) void kScan(const u32* __restrict__ occ,
                                              u32* __restrict__ rank_,
                                              u32* __restrict__ nuni) {
    int t = threadIdx.x;
    int base = t * 128;
    u32 s = 0;
#pragma unroll 8
    for (int j = 0; j < 128; ++j) s += occ[base + j];
    __shared__ u32 a[1024];
    a[t] = s;
    __syncthreads();
    for (int d = 1; d < 1024; d <<= 1) {
        u32 v = (t >= d) ? a[t - d] : 0u;
        __syncthreads();
        a[t] += v;
        __syncthreads();
    }
    u32 run = a[t] - s;  // exclusive offset for this thread's chunk
    for (int j = 0; j < 128; ++j) {
        u32 o = occ[base + j];
        rank_[base + j] = run;
        run += o;
    }
    if (t == 1023) nuni[0] = a[1023];
}

// ---------------- kernel C: final MLP, write feat, scatter-max into voxel_feat (mapped) ----------------
__global__ __launch_bounds__(256) void kC(const float* __restrict__ pc,
                                          const u32* __restrict__ keys,
                                          const u32* __restrict__ rank_,
                                          const float* __restrict__ W1,
                                          const float* __restrict__ b1,
                                          const float* __restrict__ stats1,
                                          const float* __restrict__ W2,
                                          const float* __restrict__ b2,
                                          const float* __restrict__ stats2,
                                          float* __restrict__ feat_out,
                                          u32* __restrict__ vf_u) {
    int t = threadIdx.x;
    __shared__ float shx[64];
    __shared__ float shh[16][16];
    __shared__ u32 shr[16];

    int c1 = t & 15;
    float w1c[4];
#pragma unroll
    for (int i = 0; i < 4; ++i) w1c[i] = W1[i * 16 + c1];
    float b1c = b1[c1], sc1 = stats1[c1], sf1 = stats1[16 + c1];

    int c2 = t & 63;
    float w2c[16];
#pragma unroll
    for (int k = 0; k < 16; ++k) w2c[k] = W2[k * 64 + c2];
    float b2c = b2[c2], sc2 = stats2[c2], sf2 = stats2[64 + c2];
    int psub = t >> 6;

    for (int tile = blockIdx.x; tile < NTILES; tile += gridDim.x) {
        int base = tile * 16;
        if (t < 64) shx[t] = pc[base * 4 + t];
        if (t < 16) shr[t] = rank_[keys[base + t]];
        __syncthreads();
        {
            int p = t >> 4;
            float hp = b1c + shx[p * 4 + 0] * w1c[0] + shx[p * 4 + 1] * w1c[1]
                           + shx[p * 4 + 2] * w1c[2] + shx[p * 4 + 3] * w1c[3];
            float z = hp * sc1 + sf1;
            shh[p][c1] = (z >= 0.f) ? z : SLOPE * z;
        }
        __syncthreads();
#pragma unroll
        for (int i = 0; i < 4; ++i) {
            int p = (psub << 2) + i;
            float f = b2c;
#pragma unroll
            for (int k = 0; k < 16; ++k) f += shh[p][k] * w2c[k];
            float z = f * sc2 + sf2;
            float ff = (z >= 0.f) ? z : SLOPE * z;
            feat_out[(size_t)(base + p) * 64 + c2] = ff;
            atomicMax(&vf_u[(size_t)shr[p] * 64 + c2], mapf(ff));
        }
        __syncthreads();
    }
}

// ---------------- kernel D: unmap voxel_feat in place, zero invalid rows ----------------
__global__ __launch_bounds__(256) void kD(float* __restrict__ vf, const u32* __restrict__ nuni) {
    size_t i4 = (size_t)blockIdx.x * 256 + threadIdx.x;  // quad index; N*64/4 total
    u32 nu = *nuni;
    u32 row = (u32)((i4 * 4) >> 6);
    uint4 m = ((const uint4*)vf)[i4];
    float4 o;
    if (row < nu) {
        o.x = unmapf(m.x); o.y = unmapf(m.y); o.z = unmapf(m.z); o.w = unmapf(m.w);
    } else {
        o.x = 0.f; o.y = 0.f; o.z = 0.f; o.w = 0.f;
    }
    ((float4*)vf)[i4] = o;
}

// ---------------- kernel E: write voxel_ind coords (as float values) ----------------
__global__ __launch_bounds__(256) void kE(const u32* __restrict__ occ,
                                          const u32* __restrict__ rank_,
                                          float* __restrict__ vi) {
    int c = blockIdx.x * 256 + threadIdx.x;  // < NKEY
    if (occ[c]) {
        u32 r = rank_[c];
        float4 o;
        o.x = (float)(c >> 15);          // batch id
        o.y = (float)((c >> 10) & 31);   // i0
        o.z = (float)((c >> 5) & 31);    // i1
        o.w = (float)(c & 31);           // i2
        ((float4*)vi)[r] = o;
    }
}

extern "C" void kernel_launch(void* const* d_in, const int* in_sizes, int n_in,
                              void* d_out, int out_size, void* d_ws, size_t ws_size,
                              hipStream_t stream) {
    const float* pc   = (const float*)d_in[0];
    const int*   pidx = (const int*)d_in[1];
    const float* W1   = (const float*)d_in[2];
    const float* b1   = (const float*)d_in[3];
    const float* g1   = (const float*)d_in[4];
    const float* be1  = (const float*)d_in[5];
    const float* W2   = (const float*)d_in[6];
    const float* b2   = (const float*)d_in[7];
    const float* g2   = (const float*)d_in[8];
    const float* be2  = (const float*)d_in[9];

    float* vf   = (float*)d_out;                    // [N,64]
    float* vi   = vf + (size_t)N_PTS * 64;          // [N,4]
    float* feat = vi + (size_t)N_PTS * 4;           // [N,64]

    u32* ws    = (u32*)d_ws;
    u32* keys  = ws;                 // N_PTS
    u32* occ   = ws + 480000;        // NKEY
    u32* rank_ = ws + 611072;        // NKEY
    u32* nuni  = ws + 742144;        // 1 (+pad)
    float* pA     = (float*)(ws + 742160);  // NBLK_A*14
    float* stats1 = (float*)(ws + 745744);  // 32
    float* pB     = (float*)(ws + 745776);  // NBLK_B*128
    float* stats2 = (float*)(ws + 811312);  // 128

    hipMemsetAsync(occ, 0, (size_t)NKEY * 4, stream);
    hipMemsetAsync(vf, 0, (size_t)N_PTS * 64 * 4, stream);   // atomicMax init (mapped 0 = -inf)
    hipMemsetAsync(vi, 0, (size_t)N_PTS * 4 * 4, stream);

    kA<<<NBLK_A, 256, 0, stream>>>(pc, pidx, keys, occ, pA);
    kR1<<<1, 64, 0, stream>>>(pA, W1, b1, g1, be1, stats1);
    kB<<<NBLK_B, 256, 0, stream>>>(pc, W1, b1, stats1, W2, b2, pB);
    kR2<<<1, 64, 0, stream>>>(pB, g2, be2, stats2);
    kScan<<<1, 1024, 0, stream>>>(occ, rank_, nuni);
    kC<<<4096, 256, 0, stream>>>(pc, keys, rank_, W1, b1, stats1, W2, b2, stats2, feat, (u32*)vf);
    kD<<<NTILES, 256, 0, stream>>>(vf, nuni);
    kE<<<NKEY / 256, 256, 0, stream>>>(occ, rank_, vi);
}

// Round 2
// 223.767 us; speedup vs baseline: 1.2666x; 1.2666x over previous
//
#include <hip/hip_runtime.h>

typedef unsigned int u32;
typedef unsigned char u8;

#define N_PTS 480000
#define PPB   120000      // points per batch (B=4)
#define NKEY  131072      // 4 * 32^3 compact key space
#define NBLK_A 256
#define NBLK_B 512
#define NT64   7500       // N_PTS / 64
#define SLOPE 0.01f

// order-preserving float <-> uint mapping for atomicMax (0 < map(any finite float))
__device__ __forceinline__ u32 mapf(float f) {
    u32 u = __float_as_uint(f);
    return (u & 0x80000000u) ? ~u : (u | 0x80000000u);
}
__device__ __forceinline__ float unmapf(u32 m) {
    u32 u = (m & 0x80000000u) ? (m ^ 0x80000000u) : ~m;
    return __uint_as_float(u);
}

// ---------------- kernel A: keys, occupancy bytes, x-moment partials ----------------
__global__ __launch_bounds__(256) void kA(const float* __restrict__ pc,
                                          const int* __restrict__ pidx,
                                          u32* __restrict__ keys,
                                          u8* __restrict__ occ,
                                          float* __restrict__ pA) {
    int t = threadIdx.x;
    float a[14];
#pragma unroll
    for (int j = 0; j < 14; ++j) a[j] = 0.f;

    for (int n = blockIdx.x * 256 + t; n < N_PTS; n += gridDim.x * 256) {
        float4 x = ((const float4*)pc)[n];
        a[0] += x.x; a[1] += x.y; a[2] += x.z; a[3] += x.w;
        a[4] += x.x * x.x; a[5] += x.x * x.y; a[6]  += x.x * x.z; a[7]  += x.x * x.w;
        a[8] += x.y * x.y; a[9] += x.y * x.z; a[10] += x.y * x.w;
        a[11] += x.z * x.z; a[12] += x.z * x.w; a[13] += x.w * x.w;

        int i0 = pidx[3 * n], i1 = pidx[3 * n + 1], i2 = pidx[3 * n + 2];
        int bid = n / PPB;
        u32 key = (u32)(bid * 32768 + i0 * 1024 + i1 * 32 + i2);
        keys[n] = key;
        occ[key] = (u8)1;
    }

    __shared__ float red[256];
    for (int j = 0; j < 14; ++j) {
        red[t] = a[j];
        __syncthreads();
        for (int s = 128; s > 0; s >>= 1) {
            if (t < s) red[t] += red[t + s];
            __syncthreads();
        }
        if (t == 0) pA[blockIdx.x * 14 + j] = red[0];
        __syncthreads();
    }
}

// ---------------- kernel R1: reduce x-moments -> layer-1 BN scale/shift ----------------
__global__ __launch_bounds__(64) void kR1(const float* __restrict__ pA,
                                          const float* __restrict__ W1,
                                          const float* __restrict__ b1,
                                          const float* __restrict__ g1,
                                          const float* __restrict__ be1,
                                          float* __restrict__ stats1) {
    __shared__ double S[14];
    int t = threadIdx.x;
    if (t < 14) {
        double s = 0.0;
        for (int b = 0; b < NBLK_A; ++b) s += pA[b * 14 + t];
        S[t] = s;
    }
    __syncthreads();
    if (t < 16) {
        int c = t;
        double w[4];
#pragma unroll
        for (int i = 0; i < 4; ++i) w[i] = W1[i * 16 + c];
        double sx[4] = { S[0], S[1], S[2], S[3] };
        auto sxx = [&](int i, int j) -> double {
            if (i > j) { int k = i; i = j; j = k; }
            int base = (i == 0) ? 4 : (i == 1) ? 8 : (i == 2) ? 11 : 13;
            return S[base + (j - i)];
        };
        double su = 0.0;
        for (int i = 0; i < 4; ++i) su += sx[i] * w[i];
        double q = 0.0;
        for (int i = 0; i < 4; ++i)
            for (int j = 0; j < 4; ++j) q += w[i] * w[j] * sxx(i, j);
        double b = (double)b1[c];
        double sum   = su + b * (double)N_PTS;
        double sumsq = q + 2.0 * b * su + (double)N_PTS * b * b;
        double mean = sum / (double)N_PTS;
        double var  = sumsq / (double)N_PTS - mean * mean;
        float inv = rsqrtf((float)(var + 1e-5));
        float sc = g1[c] * inv;
        stats1[c]      = sc;
        stats1[16 + c] = be1[c] - (float)mean * sc;
    }
}

// ---------------- kernel B: per-channel sum/sumsq of layer-2 pre-activation (64-pt tiles) ----------------
__global__ __launch_bounds__(256) void kB(const float* __restrict__ pc,
                                          const float* __restrict__ W1,
                                          const float* __restrict__ b1,
                                          const float* __restrict__ stats1,
                                          const float* __restrict__ W2,
                                          const float* __restrict__ b2,
                                          float* __restrict__ pB) {
    int t = threadIdx.x;
    __shared__ float shx[256];
    __shared__ float shh[64][16];

    int c1 = t & 15;
    float w1c[4];
#pragma unroll
    for (int i = 0; i < 4; ++i) w1c[i] = W1[i * 16 + c1];
    float b1c = b1[c1], sc1 = stats1[c1], sf1 = stats1[16 + c1];

    int c2 = t & 63;
    float w2c[16];
#pragma unroll
    for (int k = 0; k < 16; ++k) w2c[k] = W2[k * 64 + c2];
    float b2c = b2[c2];
    int p0 = t >> 4;
    int pg = t >> 6;

    float accf = 0.f, accf2 = 0.f;
    for (int tile = blockIdx.x; tile < NT64; tile += gridDim.x) {
        int base = tile * 64;
        shx[t] = pc[base * 4 + t];
        __syncthreads();
#pragma unroll
        for (int i = 0; i < 4; ++i) {
            int p = p0 + 16 * i;
            float hp = b1c + shx[p * 4 + 0] * w1c[0] + shx[p * 4 + 1] * w1c[1]
                           + shx[p * 4 + 2] * w1c[2] + shx[p * 4 + 3] * w1c[3];
            float z = hp * sc1 + sf1;
            shh[p][c1] = (z >= 0.f) ? z : SLOPE * z;
        }
        __syncthreads();
#pragma unroll
        for (int j = 0; j < 16; ++j) {
            int p = pg + 4 * j;
            float f = b2c;
#pragma unroll
            for (int k = 0; k < 16; ++k) f += shh[p][k] * w2c[k];
            accf += f;
            accf2 += f * f;
        }
        __syncthreads();
    }

    __shared__ float r1[256], r2[256];
    r1[t] = accf; r2[t] = accf2;
    __syncthreads();
    if (t < 64) {
        float s1 = r1[t] + r1[t + 64] + r1[t + 128] + r1[t + 192];
        float s2 = r2[t] + r2[t + 64] + r2[t + 128] + r2[t + 192];
        pB[blockIdx.x * 128 + t]      = s1;
        pB[blockIdx.x * 128 + 64 + t] = s2;
    }
}

// ---------------- kernel R2: reduce layer-2 stats -> BN scale/shift ----------------
__global__ __launch_bounds__(64) void kR2(const float* __restrict__ pB,
                                          const float* __restrict__ g2,
                                          const float* __restrict__ be2,
                                          float* __restrict__ stats2) {
    int c = threadIdx.x;
    double sf = 0.0, sf2 = 0.0;
    for (int b = 0; b < NBLK_B; ++b) {
        sf  += pB[b * 128 + c];
        sf2 += pB[b * 128 + 64 + c];
    }
    double mean = sf / (double)N_PTS;
    double var  = sf2 / (double)N_PTS - mean * mean;
    float inv = rsqrtf((float)(var + 1e-5));
    float sc = g2[c] * inv;
    stats2[c]      = sc;
    stats2[64 + c] = be2[c] - (float)mean * sc;
}

// ---------------- scan pass 1: per-block sums of occupancy bytes ----------------
__global__ __launch_bounds__(256) void kS1(const u32* __restrict__ occ32,
                                           u32* __restrict__ bs) {
    int t = threadIdx.x, b = blockIdx.x;
    u32 v = occ32[b * 256 + t];     // 4 occupancy bytes (each 0/1)
    u32 c = __popc(v);
    __shared__ u32 red[256];
    red[t] = c;
    __syncthreads();
    for (int s = 128; s > 0; s >>= 1) {
        if (t < s) red[t] += red[t + s];
        __syncthreads();
    }
    if (t == 0) bs[b] = red[0];
}

// ---------------- scan pass 2: write exclusive rank per key + n_uni ----------------
__global__ __launch_bounds__(256) void kS2(const u32* __restrict__ occ32,
                                           const u32* __restrict__ bs,
                                           u32* __restrict__ rank_,
                                           u32* __restrict__ nuni) {
    int t = threadIdx.x, b = blockIdx.x;
    __shared__ u32 sbs[128];
    __shared__ u32 sexcl;
    if (t < 128) sbs[t] = bs[t];
    __syncthreads();
    if (t == 0) {
        u32 s = 0;
        for (int i = 0; i < b; ++i) s += sbs[i];
        sexcl = s;
    }
    u32 v = occ32[b * 256 + t];
    u32 c = __popc(v);
    __shared__ u32 sc[256];
    sc[t] = c;
    __syncthreads();
    for (int d = 1; d < 256; d <<= 1) {
        u32 x = (t >= d) ? sc[t - d] : 0u;
        __syncthreads();
        sc[t] += x;
        __syncthreads();
    }
    u32 run = sexcl + sc[t] - c;   // exclusive prefix for this thread's 4 keys
    int base = b * 1024 + t * 4;
#pragma unroll
    for (int j = 0; j < 4; ++j) {
        rank_[base + j] = run;
        run += (v >> (8 * j)) & 0xffu;
    }
    if (b == 127 && t == 255) nuni[0] = run;
}

// ---------------- kernel C: final MLP, write feat, scatter-max into vf rows <131072 (mapped) ----------------
__global__ __launch_bounds__(256) void kC(const float* __restrict__ pc,
                                          const u32* __restrict__ keys,
                                          const u32* __restrict__ rank_,
                                          const float* __restrict__ W1,
                                          const float* __restrict__ b1,
                                          const float* __restrict__ stats1,
                                          const float* __restrict__ W2,
                                          const float* __restrict__ b2,
                                          const float* __restrict__ stats2,
                                          float* __restrict__ feat_out,
                                          u32* __restrict__ vf_u) {
    int t = threadIdx.x;
    __shared__ float shx[256];
    __shared__ float shh[64][16];
    __shared__ u32 shr[64];

    int c1 = t & 15;
    float w1c[4];
#pragma unroll
    for (int i = 0; i < 4; ++i) w1c[i] = W1[i * 16 + c1];
    float b1c = b1[c1], sc1 = stats1[c1], sf1 = stats1[16 + c1];

    int c2 = t & 63;
    float w2c[16];
#pragma unroll
    for (int k = 0; k < 16; ++k) w2c[k] = W2[k * 64 + c2];
    float b2c = b2[c2], sc2 = stats2[c2], sf2 = stats2[64 + c2];
    int p0 = t >> 4;
    int pg = t >> 6;

    for (int tile = blockIdx.x; tile < NT64; tile += gridDim.x) {
        int base = tile * 64;
        shx[t] = pc[base * 4 + t];
        if (t < 64) shr[t] = rank_[keys[base + t]];
        __syncthreads();
#pragma unroll
        for (int i = 0; i < 4; ++i) {
            int p = p0 + 16 * i;
            float hp = b1c + shx[p * 4 + 0] * w1c[0] + shx[p * 4 + 1] * w1c[1]
                           + shx[p * 4 + 2] * w1c[2] + shx[p * 4 + 3] * w1c[3];
            float z = hp * sc1 + sf1;
            shh[p][c1] = (z >= 0.f) ? z : SLOPE * z;
        }
        __syncthreads();
#pragma unroll
        for (int j = 0; j < 16; ++j) {
            int p = pg + 4 * j;
            float f = b2c;
#pragma unroll
            for (int k = 0; k < 16; ++k) f += shh[p][k] * w2c[k];
            float z = f * sc2 + sf2;
            float ff = (z >= 0.f) ? z : SLOPE * z;
            feat_out[(size_t)(base + p) * 64 + c2] = ff;
            atomicMax(&vf_u[(size_t)shr[p] * 64 + c2], mapf(ff));
        }
        __syncthreads();
    }
}

// ---------------- kernel D: in-place unmap vf rows<nu, zero rows>=nu, zero vi tail ----------------
__global__ __launch_bounds__(256) void kD(float* __restrict__ vf,
                                          float* __restrict__ vi,
                                          const u32* __restrict__ nuni) {
    size_t i4 = (size_t)blockIdx.x * 256 + threadIdx.x;
    u32 nu = *nuni;
    if (i4 < 7680000) {            // vf: N*64/4 quads
        u32 row = (u32)(i4 >> 4);  // 16 quads per 64-float row
        float4* p = (float4*)vf + i4;
        float4 o;
        if (row < nu) {
            uint4 m = *(const uint4*)p;
            o.x = unmapf(m.x); o.y = unmapf(m.y); o.z = unmapf(m.z); o.w = unmapf(m.w);
        } else {
            o.x = 0.f; o.y = 0.f; o.z = 0.f; o.w = 0.f;
        }
        *p = o;
    } else {
        size_t q = i4 - 7680000;   // vi: one quad per row
        if (q >= nu) {
            float4 z; z.x = 0.f; z.y = 0.f; z.z = 0.f; z.w = 0.f;
            ((float4*)vi)[q] = z;
        }
    }
}

// ---------------- kernel E: write voxel_ind coords (as float values) ----------------
__global__ __launch_bounds__(256) void kE(const u8* __restrict__ occ,
                                          const u32* __restrict__ rank_,
                                          float* __restrict__ vi) {
    int c = blockIdx.x * 256 + threadIdx.x;  // < NKEY
    if (occ[c]) {
        u32 r = rank_[c];
        float4 o;
        o.x = (float)(c >> 15);          // batch id
        o.y = (float)((c >> 10) & 31);   // i0
        o.z = (float)((c >> 5) & 31);    // i1
        o.w = (float)(c & 31);           // i2
        ((float4*)vi)[r] = o;
    }
}

extern "C" void kernel_launch(void* const* d_in, const int* in_sizes, int n_in,
                              void* d_out, int out_size, void* d_ws, size_t ws_size,
                              hipStream_t stream) {
    const float* pc   = (const float*)d_in[0];
    const int*   pidx = (const int*)d_in[1];
    const float* W1   = (const float*)d_in[2];
    const float* b1   = (const float*)d_in[3];
    const float* g1   = (const float*)d_in[4];
    const float* be1  = (const float*)d_in[5];
    const float* W2   = (const float*)d_in[6];
    const float* b2   = (const float*)d_in[7];
    const float* g2   = (const float*)d_in[8];
    const float* be2  = (const float*)d_in[9];

    float* vf   = (float*)d_out;                    // [N,64]
    float* vi   = vf + (size_t)N_PTS * 64;          // [N,4]
    float* feat = vi + (size_t)N_PTS * 4;           // [N,64]

    u32* ws    = (u32*)d_ws;
    u32* keys  = ws;                        // 480000
    u8*  occ8  = (u8*)(ws + 480000);        // 131072 bytes (32768 u32)
    u32* occ32 = ws + 480000;
    u32* rank_ = ws + 512768;               // 131072
    u32* bs    = ws + 643840;               // 128
    u32* nuni  = ws + 643968;               // 1 (+pad)
    float* pA     = (float*)(ws + 643984);  // 256*14
    float* stats1 = (float*)(ws + 647568);  // 32
    float* pB     = (float*)(ws + 647600);  // 512*128
    float* stats2 = (float*)(ws + 713136);  // 128

    hipMemsetAsync(occ8, 0, (size_t)NKEY, stream);
    hipMemsetAsync(vf, 0, (size_t)NKEY * 64 * 4, stream);   // atomic init, first 131072 rows only

    kA<<<NBLK_A, 256, 0, stream>>>(pc, pidx, keys, occ8, pA);
    kR1<<<1, 64, 0, stream>>>(pA, W1, b1, g1, be1, stats1);
    kB<<<NBLK_B, 256, 0, stream>>>(pc, W1, b1, stats1, W2, b2, pB);
    kR2<<<1, 64, 0, stream>>>(pB, g2, be2, stats2);
    kS1<<<128, 256, 0, stream>>>(occ32, bs);
    kS2<<<128, 256, 0, stream>>>(occ32, bs, rank_, nuni);
    kC<<<2048, 256, 0, stream>>>(pc, keys, rank_, W1, b1, stats1, W2, b2, stats2, feat, (u32*)vf);
    kD<<<31875, 256, 0, stream>>>(vf, vi, nuni);
    kE<<<NKEY / 256, 256, 0, stream>>>(occ8, rank_, vi);
}